// Round 9
// baseline (145.525 us; speedup 1.0000x reference)
//
#include <hip/hip_runtime.h>
#include <cstdint>
#include <cstddef>

// Problem constants
#define B_    16
#define S_    1024
#define D_    512
#define P_    256
#define MAXS_ 2048

typedef unsigned short u16;
typedef unsigned int   u32;
typedef _Float16 f16;
typedef _Float16 f16x8 __attribute__((ext_vector_type(8)));
typedef float  f32x4  __attribute__((ext_vector_type(4)));
typedef unsigned short u16x4 __attribute__((ext_vector_type(4)));
typedef unsigned short u16x8 __attribute__((ext_vector_type(8)));

__device__ __forceinline__ void gld_lds16(const void* g, void* l) {
  __builtin_amdgcn_global_load_lds(
      (const __attribute__((address_space(1))) u32*)g,
      (__attribute__((address_space(3))) u32*)l, 16, 0, 0);
}

__device__ __forceinline__ u16 f2h(float f) {
  return __builtin_bit_cast(u16, (f16)f);
}
__device__ __forceinline__ float h2f(u16 h) {
  return (float)__builtin_bit_cast(f16, h);
}

// ---------------------------------------------------------------------------
// f32 -> f16 convert (data, W)  [frozen]
// ---------------------------------------------------------------------------
__global__ void convert_f16_kernel(const float* __restrict__ src, u16* __restrict__ dst, long n4) {
  long stride = (long)gridDim.x * blockDim.x;
  for (long i = (long)blockIdx.x * blockDim.x + threadIdx.x; i < n4; i += stride) {
    float4 v = ((const float4*)src)[i];
    u16x4 o;
    o[0] = f2h(v.x); o[1] = f2h(v.y); o[2] = f2h(v.z); o[3] = f2h(v.w);
    ((u16x4*)dst)[i] = o;
  }
}

// ---------------------------------------------------------------------------
// QK^T, slot-pipelined (frozen — identical to rounds 5-8 for attribution).
// ---------------------------------------------------------------------------
__global__ __launch_bounds__(512, 2) void qk_pipe(
    const u16* __restrict__ A, u16* __restrict__ Cout, float scale) {
  extern __shared__ __align__(16) char smem[];   // 4 * 32768
  const int tid  = threadIdx.x;
  const int lane = tid & 63;
  const int w    = tid >> 6;
  const int wm   = w >> 2;        // 0..1
  const int wn   = w & 3;         // 0..3
  const int lr   = lane & 15;
  const int hi   = lane >> 4;

  const int bz = blockIdx.z;
  const int I0 = blockIdx.y * 256;
  const int J0 = blockIdx.x * 256;
  const u16* Ab = A + (long)bz * (S_ * D_);

  auto stageP = [&](int s, int part) {
    if (s >= 16) return;
    char* dst = smem + (s & 3) * 32768 + part * 16384;
    const int base = part ? J0 : I0;
    const int k0 = s * 32;
    #pragma unroll
    for (int i = 0; i < 2; ++i) {
      int cid   = i * 512 + tid;
      int inner = cid >> 2;
      int c     = (cid & 3) ^ ((inner >> 1) & 3);
      gld_lds16(Ab + (size_t)(base + inner) * D_ + k0 + c * 8, dst + cid * 16);
    }
  };

  f32x4 acc[8][4] = {};

  stageP(0, 0); stageP(0, 1);
  stageP(1, 0); stageP(1, 1);
  stageP(2, 0); stageP(2, 1);
  asm volatile("s_waitcnt vmcnt(8)" ::: "memory");
  __builtin_amdgcn_s_barrier();

  for (int s = 0; s < 16; ++s) {
    const char* sl = smem + (s & 3) * 32768;
    f16x8 bf[4];
    // ---- phase 0 ----
    {
      f16x8 af[4];
      #pragma unroll
      for (int mq = 0; mq < 4; ++mq) {
        int row = wm * 128 + mq * 16 + lr;
        int cp  = hi ^ ((row >> 1) & 3);
        af[mq] = *(const f16x8*)(sl + row * 64 + cp * 16);
      }
      #pragma unroll
      for (int n = 0; n < 4; ++n) {
        int row = wn * 64 + n * 16 + lr;
        int cp  = hi ^ ((row >> 1) & 3);
        bf[n] = *(const f16x8*)(sl + 16384 + row * 64 + cp * 16);
      }
      stageP(s + 3, 0);
      __builtin_amdgcn_s_barrier();
      asm volatile("s_waitcnt lgkmcnt(0)" ::: "memory");
      __builtin_amdgcn_sched_barrier(0);
      __builtin_amdgcn_s_setprio(1);
      #pragma unroll
      for (int mq = 0; mq < 4; ++mq)
        #pragma unroll
        for (int n = 0; n < 4; ++n)
          acc[mq][n] = __builtin_amdgcn_mfma_f32_16x16x32_f16(af[mq], bf[n], acc[mq][n], 0, 0, 0);
      __builtin_amdgcn_s_setprio(0);
      __builtin_amdgcn_s_barrier();
    }
    // ---- phase 1 ----
    {
      f16x8 af[4];
      #pragma unroll
      for (int mq = 0; mq < 4; ++mq) {
        int row = wm * 128 + 64 + mq * 16 + lr;
        int cp  = hi ^ ((row >> 1) & 3);
        af[mq] = *(const f16x8*)(sl + row * 64 + cp * 16);
      }
      stageP(s + 3, 1);
      __builtin_amdgcn_s_barrier();
      asm volatile("s_waitcnt lgkmcnt(0)" ::: "memory");
      __builtin_amdgcn_sched_barrier(0);
      __builtin_amdgcn_s_setprio(1);
      #pragma unroll
      for (int mq = 0; mq < 4; ++mq)
        #pragma unroll
        for (int n = 0; n < 4; ++n)
          acc[4 + mq][n] = __builtin_amdgcn_mfma_f32_16x16x32_f16(af[mq], bf[n], acc[4 + mq][n], 0, 0, 0);
      __builtin_amdgcn_s_setprio(0);
      if (s <= 12)      asm volatile("s_waitcnt vmcnt(8)" ::: "memory");
      else if (s == 13) asm volatile("s_waitcnt vmcnt(4)" ::: "memory");
      else if (s == 14) asm volatile("s_waitcnt vmcnt(0)" ::: "memory");
      __builtin_amdgcn_s_barrier();
    }
  }

  u16* Cb = Cout + (long)bz * S_ * S_;
  const int row0 = I0 + wm * 128;
  const int col0 = J0 + wn * 64;
  #pragma unroll
  for (int m = 0; m < 8; ++m) {
    #pragma unroll
    for (int i = 0; i < 4; ++i) {
      int r = row0 + m * 16 + (hi << 2) + i;
      #pragma unroll
      for (int n = 0; n < 4; ++n) {
        int c = col0 + n * 16 + lr;
        Cb[(size_t)r * S_ + c] = f2h(acc[m][n][i] * scale);
      }
    }
  }
}

// ---------------------------------------------------------------------------
// Row stats: scores [16384][1024] f16 -> (max, 1/sumexp) float2 per row.
// [frozen]
// ---------------------------------------------------------------------------
__global__ __launch_bounds__(256) void stats_kernel(
    const u16* __restrict__ scores, float2* __restrict__ rowstat) {
  const int lane = threadIdx.x & 63;
  const int wv   = threadIdx.x >> 6;
  const long row = (long)blockIdx.x * 4 + wv;
  const u16* src = scores + row * S_;

  u16x8 a0 = *(const u16x8*)&src[lane * 16];
  u16x8 a1 = *(const u16x8*)&src[lane * 16 + 8];
  float v[16];
  #pragma unroll
  for (int j = 0; j < 8; ++j) { v[j] = h2f(a0[j]); v[8 + j] = h2f(a1[j]); }

  float mx = v[0];
  #pragma unroll
  for (int j = 1; j < 16; ++j) mx = fmaxf(mx, v[j]);
  #pragma unroll
  for (int off = 32; off > 0; off >>= 1)
    mx = fmaxf(mx, __shfl_xor(mx, off));

  const float l2e = 1.4426950408889634f;
  float sum = 0.f;
  #pragma unroll
  for (int j = 0; j < 16; ++j) sum += exp2f((v[j] - mx) * l2e);
  #pragma unroll
  for (int off = 32; off > 0; off >>= 1)
    sum += __shfl_xor(sum, off);

  if (lane == 0) rowstat[row] = make_float2(mx, 1.f / sum);
}

// ---------------------------------------------------------------------------
// pv_stream: out[b][:S] = softmax(scores[b]) @ VWT[b]^T + bias.
//   ZERO LDS, ZERO barriers (VWT is L2-resident: 512 KB/batch; scores
//   streamed once — staging them was pure overhead, common-mistake #7).
//   Block 128q x 64P: 4 waves 4Mx1N, wave tile 32x64 (MF2 x NF4).
//   Per K-tile(32) per wave: 2 A-loads (b128) + 4 B-loads (b128, f16 bits
//   feed MFMA directly), in-reg exp2 on A (1/l folded into epilogue as
//   row-scale), 8 MFMA. Hand 2-deep pipeline with named even/odd regs
//   (rule #20); WAR register deps keep the compiler's schedule honest;
//   compiler inserts all waitcnts. grid (4,16,16): yt>=8 zero-fills tail.
// ---------------------------------------------------------------------------
__global__ __launch_bounds__(256, 2) void pv_stream(
    const u16* __restrict__ scores, const u16* __restrict__ VWT,
    const float2* __restrict__ rowstat,
    float* __restrict__ out, const float* __restrict__ bias) {
  const int tid  = threadIdx.x;
  const int lane = tid & 63;
  const int wm   = tid >> 6;        // 0..3 (M split)
  const int lr   = lane & 15;
  const int hi   = lane >> 4;
  const int bz   = blockIdx.z;
  const int yt   = blockIdx.y;

  float* ob = out + (long)bz * MAXS_ * P_;
  if (yt >= 8) {                    // zero tail rows 1024..2047
    float4* o = (float4*)(ob + (size_t)yt * 128 * P_);
    for (int i = tid; i < 128 * P_ / 4; i += 256)
      o[i] = make_float4(0.f, 0.f, 0.f, 0.f);
    return;
  }

  const int q0 = yt * 128;
  const int J0 = blockIdx.x * 64;
  const int r0 = q0 + wm * 32;      // wave's A-row base
  const u16* sA = scores + ((long)bz * S_ + r0) * S_;
  const u16* sB = VWT + (long)bz * P_ * S_ + (size_t)J0 * S_;
  const float l2e = 1.4426950408889634f;

  // per-lane softmax max for the two A-frag rows (r0+lr, r0+16+lr)
  const float nml0 = -rowstat[(long)bz * S_ + r0 + lr].x * l2e;
  const float nml1 = -rowstat[(long)bz * S_ + r0 + 16 + lr].x * l2e;

  f32x4 acc[2][4] = {};

  u16x8 a0[2], b0[4], a1[2], b1[4];

  auto loadAll = [&](u16x8 (&a)[2], u16x8 (&b)[4], int t) {
    const int k = t * 32 + hi * 8;
    #pragma unroll
    for (int m = 0; m < 2; ++m)
      a[m] = *(const u16x8*)(sA + (size_t)(m * 16 + lr) * S_ + k);
    #pragma unroll
    for (int n = 0; n < 4; ++n)
      b[n] = *(const u16x8*)(sB + (size_t)(n * 16 + lr) * S_ + k);
  };
  auto compute = [&](u16x8 (&a)[2], u16x8 (&b)[4]) {
    f16x8 pa[2];
    #pragma unroll
    for (int m = 0; m < 2; ++m) {
      const float nml = m ? nml1 : nml0;
      #pragma unroll
      for (int j = 0; j < 8; ++j)
        pa[m][j] = (f16)exp2f(fmaf(h2f(a[m][j]), l2e, nml));
    }
    #pragma unroll
    for (int m = 0; m < 2; ++m)
      #pragma unroll
      for (int n = 0; n < 4; ++n)
        acc[m][n] = __builtin_amdgcn_mfma_f32_16x16x32_f16(
            pa[m], __builtin_bit_cast(f16x8, b[n]), acc[m][n], 0, 0, 0);
  };

  loadAll(a0, b0, 0);
  for (int t = 0; t < 30; t += 2) {
    loadAll(a1, b1, t + 1);
    compute(a0, b0);                // tile t   (WAR protects a0/b0 reload)
    loadAll(a0, b0, t + 2);
    compute(a1, b1);                // tile t+1
  }
  loadAll(a1, b1, 31);
  compute(a0, b0);                  // tile 30
  compute(a1, b1);                  // tile 31

  // epilogue: out = acc * (1/l)[row] + bias[col]. C/D: col=lane&15,
  // row=(lane>>4)*4+reg.
  float bv[4];
  #pragma unroll
  for (int n = 0; n < 4; ++n) bv[n] = bias[J0 + n * 16 + lr];
  #pragma unroll
  for (int m = 0; m < 2; ++m) {
    #pragma unroll
    for (int i = 0; i < 4; ++i) {
      const int r = r0 + m * 16 + (hi << 2) + i;
      const float il = rowstat[(long)bz * S_ + r].y;
      #pragma unroll
      for (int n = 0; n < 4; ++n)
        ob[(size_t)r * P_ + J0 + n * 16 + lr] = acc[m][n][i] * il + bv[n];
    }
  }
}

// ---------------------------------------------------------------------------
// VW GEMM (frozen — identical to rounds 7-8): C[MxN] = A[MxK]*B[NxK]^T, f16.
// ---------------------------------------------------------------------------
template<int KK, int BM, int BN, int NW, int WNS>
__global__ __launch_bounds__(NW * 64, 2) void gemm_nt_small(
    const u16* __restrict__ A, const u16* __restrict__ Bm,
    u16* __restrict__ C, long sAb, long sBb, long sCb, int LDC) {
  constexpr int T   = NW * 64;
  constexpr int WMS = NW / WNS;
  constexpr int MF  = BM / (WMS * 16);
  constexpr int NF  = BN / (WNS * 16);
  constexpr int LA  = BM * 8 / T;
  constexpr int LB  = BN * 8 / T;
  constexpr int SZ  = (BM + BN) * 128;
  constexpr int NT  = KK / 64;

  extern __shared__ __align__(16) char smem[];
  const int tid  = threadIdx.x;
  const int lane = tid & 63;
  const int w    = tid >> 6;
  const int wm   = w / WNS;
  const int wn   = w % WNS;
  const int lr   = lane & 15;
  const int hi   = lane >> 4;

  const int bz = blockIdx.z;
  const int I0 = blockIdx.y * BM;
  const int J0 = blockIdx.x * BN;
  const u16* Ab = A  + (long)bz * sAb;
  const u16* Bb = Bm + (long)bz * sBb;

  auto stage = [&](int buf, int k0) {
    char* sA = smem + buf * SZ;
    char* sB = sA + BM * 128;
    #pragma unroll
    for (int i = 0; i < LA; ++i) {
      int cid = i * T + tid;
      int row = cid >> 3;
      int c   = (cid & 7) ^ (row & 7);
      gld_lds16(Ab + (size_t)(I0 + row) * KK + k0 + c * 8, sA + cid * 16);
    }
    #pragma unroll
    for (int i = 0; i < LB; ++i) {
      int cid = i * T + tid;
      int row = cid >> 3;
      int c   = (cid & 7) ^ (row & 7);
      gld_lds16(Bb + (size_t)(J0 + row) * KK + k0 + c * 8, sB + cid * 16);
    }
  };

  f32x4 acc[MF][NF] = {};
  stage(0, 0);
  for (int t = 0; t < NT; ++t) {
    const char* lA = smem + (t & 1) * SZ;
    const char* lB = lA + BM * 128;
    if (t + 1 < NT) {
      stage((t + 1) & 1, (t + 1) * 64);
      asm volatile("s_waitcnt vmcnt(%0)" :: "i"(LA + LB) : "memory");
    } else {
      asm volatile("s_waitcnt vmcnt(0)" ::: "memory");
    }
    __builtin_amdgcn_s_barrier();
    __builtin_amdgcn_sched_barrier(0);
    #pragma unroll
    for (int kk = 0; kk < 2; ++kk) {
      f16x8 af[MF], bfv[NF];
      #pragma unroll
      for (int m = 0; m < MF; ++m) {
        int row = wm * (MF * 16) + m * 16 + lr;
        int cp  = (kk * 4 + hi) ^ (row & 7);
        af[m] = *(const f16x8*)(lA + ((row * 8 + cp) << 4));
      }
      #pragma unroll
      for (int n = 0; n < NF; ++n) {
        int row = wn * (NF * 16) + n * 16 + lr;
        int cp  = (kk * 4 + hi) ^ (row & 7);
        bfv[n] = *(const f16x8*)(lB + ((row * 8 + cp) << 4));
      }
      __builtin_amdgcn_s_setprio(1);
      #pragma unroll
      for (int m = 0; m < MF; ++m)
        #pragma unroll
        for (int n = 0; n < NF; ++n)
          acc[m][n] = __builtin_amdgcn_mfma_f32_16x16x32_f16(af[m], bfv[n], acc[m][n], 0, 0, 0);
      __builtin_amdgcn_s_setprio(0);
    }
    __builtin_amdgcn_sched_barrier(0);
    __builtin_amdgcn_s_barrier();
  }

  const int row0 = I0 + wm * (MF * 16);
  const int col0 = J0 + wn * (NF * 16);
  #pragma unroll
  for (int m = 0; m < MF; ++m)
    #pragma unroll
    for (int i = 0; i < 4; ++i) {
      int r = row0 + m * 16 + (hi << 2) + i;
      #pragma unroll
      for (int n = 0; n < NF; ++n)
        C[(long)bz * sCb + (size_t)r * LDC + col0 + n * 16 + lr] = f2h(acc[m][n][i]);
    }
}

// ---------------------------------------------------------------------------
extern "C" void kernel_launch(void* const* d_in, const int* in_sizes, int n_in,
                              void* d_out, int out_size, void* d_ws, size_t ws_size,
                              hipStream_t stream) {
  const float* data = (const float*)d_in[0];   // [16][1024][512]
  const float* W    = (const float*)d_in[1];   // [256][512]
  const float* bias = (const float*)d_in[2];   // [256]
  float* out = (float*)d_out;                  // [16][2048][256]
  char*  ws  = (char*)d_ws;

  const size_t MB = 1024 * 1024;
  u16*    dataH   = (u16*)(ws);                // 16 MB  [B][S][D] f16
  u16*    Wh      = (u16*)(ws + 16 * MB);      // 256 KB [P][D] f16
  u16*    scoresH = (u16*)(ws + 17 * MB);      // 32 MB  [B][S][S] f16
  u16*    VWT     = (u16*)(ws + 49 * MB);      // 8 MB   [B][P][S] f16
  float2* rowstat = (float2*)(ws + 57 * MB);   // 128 KB [B][S] (m, 1/l)

  const float scale = 0.04419417382415922f;    // 1/sqrt(512)

  constexpr int SMEM_QK = 4 * 32768;             // 128 KB
  constexpr int SMEM_VW = 2 * (64 + 128) * 128;  // 48 KB

  (void)hipFuncSetAttribute((const void*)&qk_pipe,
                      hipFuncAttributeMaxDynamicSharedMemorySize, SMEM_QK);
  (void)hipFuncSetAttribute((const void*)&gemm_nt_small<512, 64, 128, 4, 2>,
                      hipFuncAttributeMaxDynamicSharedMemorySize, SMEM_VW);

  convert_f16_kernel<<<2048, 256, 0, stream>>>(data, dataH, (long)B_ * S_ * D_ / 4);
  convert_f16_kernel<<<64, 256, 0, stream>>>(W, Wh, (long)P_ * D_ / 4);

  // VWT[b] = Wh (256x512) @ dataH[b]^T -> [256][1024] f16
  gemm_nt_small<512, 64, 128, 4, 2><<<dim3(8, 4, 16), 256, SMEM_VW, stream>>>(
      Wh, dataH, VWT, 0L, (long)S_ * D_, (long)P_ * S_, S_);

  // scoresH[b] = scale * dataH[b] @ dataH[b]^T -> [1024][1024] f16
  qk_pipe<<<dim3(4, 4, 16), 512, SMEM_QK, stream>>>(dataH, scoresH, scale);

  // rowstat = per-row (max, 1/sumexp)
  stats_kernel<<<4096, 256, 0, stream>>>(scoresH, rowstat);

  // out[b][:S] = softmax(scoresH[b]) @ VWT[b]^T + bias; tail rows zeroed
  pv_stream<<<dim3(4, 16, 16), 256, 0, stream>>>(
      scoresH, VWT, rowstat, out, bias);
}

// Round 10
// 83.428 us; speedup vs baseline: 1.7443x; 1.7443x over previous
//
#include <hip/hip_runtime.h>
#include <cstdint>
#include <cstddef>

// Problem constants
#define B_    16
#define S_    1024
#define D_    512
#define P_    256
#define MAXS_ 2048

typedef unsigned short u16;
typedef unsigned int   u32;
typedef _Float16 f16;
typedef _Float16 f16x8 __attribute__((ext_vector_type(8)));
typedef float  f32x4  __attribute__((ext_vector_type(4)));
typedef unsigned short u16x4 __attribute__((ext_vector_type(4)));
typedef unsigned short u16x8 __attribute__((ext_vector_type(8)));

__device__ __forceinline__ void gld_lds16(const void* g, void* l) {
  __builtin_amdgcn_global_load_lds(
      (const __attribute__((address_space(1))) u32*)g,
      (__attribute__((address_space(3))) u32*)l, 16, 0, 0);
}

__device__ __forceinline__ u16 f2h(float f) {
  return __builtin_bit_cast(u16, (f16)f);
}
__device__ __forceinline__ float h2f(u16 h) {
  return (float)__builtin_bit_cast(f16, h);
}

// ---------------------------------------------------------------------------
// f32 -> f16 convert (data, W)  [frozen]
// ---------------------------------------------------------------------------
__global__ void convert_f16_kernel(const float* __restrict__ src, u16* __restrict__ dst, long n4) {
  long stride = (long)gridDim.x * blockDim.x;
  for (long i = (long)blockIdx.x * blockDim.x + threadIdx.x; i < n4; i += stride) {
    float4 v = ((const float4*)src)[i];
    u16x4 o;
    o[0] = f2h(v.x); o[1] = f2h(v.y); o[2] = f2h(v.z); o[3] = f2h(v.w);
    ((u16x4*)dst)[i] = o;
  }
}

// ---------------------------------------------------------------------------
// QK^T, slot-pipelined (frozen — identical to rounds 5-9 for attribution).
// ---------------------------------------------------------------------------
__global__ __launch_bounds__(512, 2) void qk_pipe(
    const u16* __restrict__ A, u16* __restrict__ Cout, float scale) {
  extern __shared__ __align__(16) char smem[];   // 4 * 32768
  const int tid  = threadIdx.x;
  const int lane = tid & 63;
  const int w    = tid >> 6;
  const int wm   = w >> 2;        // 0..1
  const int wn   = w & 3;         // 0..3
  const int lr   = lane & 15;
  const int hi   = lane >> 4;

  const int bz = blockIdx.z;
  const int I0 = blockIdx.y * 256;
  const int J0 = blockIdx.x * 256;
  const u16* Ab = A + (long)bz * (S_ * D_);

  auto stageP = [&](int s, int part) {
    if (s >= 16) return;
    char* dst = smem + (s & 3) * 32768 + part * 16384;
    const int base = part ? J0 : I0;
    const int k0 = s * 32;
    #pragma unroll
    for (int i = 0; i < 2; ++i) {
      int cid   = i * 512 + tid;
      int inner = cid >> 2;
      int c     = (cid & 3) ^ ((inner >> 1) & 3);
      gld_lds16(Ab + (size_t)(base + inner) * D_ + k0 + c * 8, dst + cid * 16);
    }
  };

  f32x4 acc[8][4] = {};

  stageP(0, 0); stageP(0, 1);
  stageP(1, 0); stageP(1, 1);
  stageP(2, 0); stageP(2, 1);
  asm volatile("s_waitcnt vmcnt(8)" ::: "memory");
  __builtin_amdgcn_s_barrier();

  for (int s = 0; s < 16; ++s) {
    const char* sl = smem + (s & 3) * 32768;
    f16x8 bf[4];
    // ---- phase 0 ----
    {
      f16x8 af[4];
      #pragma unroll
      for (int mq = 0; mq < 4; ++mq) {
        int row = wm * 128 + mq * 16 + lr;
        int cp  = hi ^ ((row >> 1) & 3);
        af[mq] = *(const f16x8*)(sl + row * 64 + cp * 16);
      }
      #pragma unroll
      for (int n = 0; n < 4; ++n) {
        int row = wn * 64 + n * 16 + lr;
        int cp  = hi ^ ((row >> 1) & 3);
        bf[n] = *(const f16x8*)(sl + 16384 + row * 64 + cp * 16);
      }
      stageP(s + 3, 0);
      __builtin_amdgcn_s_barrier();
      asm volatile("s_waitcnt lgkmcnt(0)" ::: "memory");
      __builtin_amdgcn_sched_barrier(0);
      __builtin_amdgcn_s_setprio(1);
      #pragma unroll
      for (int mq = 0; mq < 4; ++mq)
        #pragma unroll
        for (int n = 0; n < 4; ++n)
          acc[mq][n] = __builtin_amdgcn_mfma_f32_16x16x32_f16(af[mq], bf[n], acc[mq][n], 0, 0, 0);
      __builtin_amdgcn_s_setprio(0);
      __builtin_amdgcn_s_barrier();
    }
    // ---- phase 1 ----
    {
      f16x8 af[4];
      #pragma unroll
      for (int mq = 0; mq < 4; ++mq) {
        int row = wm * 128 + 64 + mq * 16 + lr;
        int cp  = hi ^ ((row >> 1) & 3);
        af[mq] = *(const f16x8*)(sl + row * 64 + cp * 16);
      }
      stageP(s + 3, 1);
      __builtin_amdgcn_s_barrier();
      asm volatile("s_waitcnt lgkmcnt(0)" ::: "memory");
      __builtin_amdgcn_sched_barrier(0);
      __builtin_amdgcn_s_setprio(1);
      #pragma unroll
      for (int mq = 0; mq < 4; ++mq)
        #pragma unroll
        for (int n = 0; n < 4; ++n)
          acc[4 + mq][n] = __builtin_amdgcn_mfma_f32_16x16x32_f16(af[mq], bf[n], acc[4 + mq][n], 0, 0, 0);
      __builtin_amdgcn_s_setprio(0);
      if (s <= 12)      asm volatile("s_waitcnt vmcnt(8)" ::: "memory");
      else if (s == 13) asm volatile("s_waitcnt vmcnt(4)" ::: "memory");
      else if (s == 14) asm volatile("s_waitcnt vmcnt(0)" ::: "memory");
      __builtin_amdgcn_s_barrier();
    }
  }

  u16* Cb = Cout + (long)bz * S_ * S_;
  const int row0 = I0 + wm * 128;
  const int col0 = J0 + wn * 64;
  #pragma unroll
  for (int m = 0; m < 8; ++m) {
    #pragma unroll
    for (int i = 0; i < 4; ++i) {
      int r = row0 + m * 16 + (hi << 2) + i;
      #pragma unroll
      for (int n = 0; n < 4; ++n) {
        int c = col0 + n * 16 + lr;
        Cb[(size_t)r * S_ + c] = f2h(acc[m][n][i] * scale);
      }
    }
  }
}

// ---------------------------------------------------------------------------
// Row stats: scores [16384][1024] f16 -> (max, 1/sumexp) float2 per row.
// [frozen]
// ---------------------------------------------------------------------------
__global__ __launch_bounds__(256) void stats_kernel(
    const u16* __restrict__ scores, float2* __restrict__ rowstat) {
  const int lane = threadIdx.x & 63;
  const int wv   = threadIdx.x >> 6;
  const long row = (long)blockIdx.x * 4 + wv;
  const u16* src = scores + row * S_;

  u16x8 a0 = *(const u16x8*)&src[lane * 16];
  u16x8 a1 = *(const u16x8*)&src[lane * 16 + 8];
  float v[16];
  #pragma unroll
  for (int j = 0; j < 8; ++j) { v[j] = h2f(a0[j]); v[8 + j] = h2f(a1[j]); }

  float mx = v[0];
  #pragma unroll
  for (int j = 1; j < 16; ++j) mx = fmaxf(mx, v[j]);
  #pragma unroll
  for (int off = 32; off > 0; off >>= 1)
    mx = fmaxf(mx, __shfl_xor(mx, off));

  const float l2e = 1.4426950408889634f;
  float sum = 0.f;
  #pragma unroll
  for (int j = 0; j < 16; ++j) sum += exp2f((v[j] - mx) * l2e);
  #pragma unroll
  for (int off = 32; off > 0; off >>= 1)
    sum += __shfl_xor(sum, off);

  if (lane == 0) rowstat[row] = make_float2(mx, 1.f / sum);
}

// ---------------------------------------------------------------------------
// pv_slot: out[b][:S] = softmax(scores[b]) @ VWT[b]^T + bias.
//   The qk slot schedule at PV geometry. Block 64q x 128p, 4 waves 2Mx2N
//   (wave tile 32x64). K=1024 = 16 slots of BK=64 (128B LDS rows).
//   LDS: A ring3 x 8KB + B ring3 x 16KB = 72 KB -> 2 blocks/CU (8 waves/CU).
//   B staged via gld_lds with m201-style XOR-8 swizzle (pre-swizzled global
//   source + LINEAR LDS dest + swizzled ds_read = rule #21): 2-way = free.
//   A: coalesced u16x8 reg-load (pre-swizzled chunk), exp2((s-m)*l2e)*(1/l)
//   in-reg, linear ds_write_b128. Staged 2 slots ahead; ONE counted vmcnt(6)
//   + ONE barrier per slot (drain only at s=14). Fully unrolled: all ring /
//   reg indices compile-time (rule #20). grid (2,32,16): yt>=16 zero-fills.
// ---------------------------------------------------------------------------
__global__ __launch_bounds__(256, 2) void pv_slot(
    const u16* __restrict__ scores, const u16* __restrict__ VWT,
    const float2* __restrict__ rowstat,
    float* __restrict__ out, const float* __restrict__ bias) {
  extern __shared__ __align__(16) char smem[];   // A 3*8K @0, B 3*16K @24K
  const int tid  = threadIdx.x;
  const int lane = tid & 63;
  const int w    = tid >> 6;
  const int wm   = w >> 1;        // 0..1
  const int wn   = w & 1;         // 0..1
  const int lr   = lane & 15;
  const int hi   = lane >> 4;
  const int bz   = blockIdx.z;
  const int yt   = blockIdx.y;
  const int J0   = blockIdx.x * 128;

  float* ob = out + (long)bz * MAXS_ * P_;
  if (yt >= 16) {                  // zero rows [yt*64,+64) x cols [J0,+128)
    #pragma unroll 2
    for (int i = tid; i < 64 * 32; i += 256) {
      int r  = i >> 5;
      int c4 = i & 31;
      *((float4*)(ob + (size_t)(yt * 64 + r) * P_ + J0) + c4) =
          make_float4(0.f, 0.f, 0.f, 0.f);
    }
    return;
  }

  const int q0 = yt * 64;
  const u16* sA = scores + ((long)bz * S_ + q0) * S_;
  const u16* Vb = VWT + (long)bz * P_ * S_ + (size_t)J0 * S_;
  const float l2e = 1.4426950408889634f;

  // A staging: this thread owns rows ar0, ar1 (one 16B chunk each per slot)
  const int ar0 = tid >> 3;
  const int ar1 = 32 + (tid >> 3);
  const int ac  = tid & 7;                     // LDS chunk index (linear)
  const int c0  = ac ^ (ar0 & 7);              // pre-swizzled global chunk
  const int c1  = ac ^ (ar1 & 7);
  const float2 st0 = rowstat[(long)bz * S_ + q0 + ar0];
  const float2 st1 = rowstat[(long)bz * S_ + q0 + ar1];
  const float nml0 = -st0.x * l2e, il0 = st0.y;
  const float nml1 = -st1.x * l2e, il1 = st1.y;

  auto loadA = [&](int s, u16x8 (&r)[2]) {
    r[0] = *(const u16x8*)(sA + (size_t)ar0 * S_ + s * 64 + c0 * 8);
    r[1] = *(const u16x8*)(sA + (size_t)ar1 * S_ + s * 64 + c1 * 8);
  };
  auto writeA = [&](int buf, u16x8 (&r)[2]) {
    char* dA = smem + buf * 8192;
    u16x8 p0, p1;
    #pragma unroll
    for (int j = 0; j < 8; ++j) {
      p0[j] = f2h(exp2f(fmaf(h2f(r[0][j]), l2e, nml0)) * il0);
      p1[j] = f2h(exp2f(fmaf(h2f(r[1][j]), l2e, nml1)) * il1);
    }
    *(u16x8*)(dA + (size_t)tid * 16)         = p0;   // chunk cid = tid
    *(u16x8*)(dA + (size_t)(256 + tid) * 16) = p1;   // chunk cid = 256+tid
  };
  auto stageB = [&](int s, int buf) {
    char* dB = smem + 24576 + buf * 16384;
    #pragma unroll
    for (int i = 0; i < 4; ++i) {
      int cid = i * 256 + tid;
      int row = cid >> 3;
      int c   = (cid & 7) ^ (row & 7);
      gld_lds16(Vb + (size_t)row * S_ + s * 64 + c * 8, dB + cid * 16);
    }
  };

  f32x4 acc[2][4] = {};
  u16x8 rA[2][2];

  // ---- prologue: slots 0,1 in flight (12 VM ops) ----
  loadA(0, rA[0]);
  __builtin_amdgcn_sched_barrier(0);
  stageB(0, 0);
  __builtin_amdgcn_sched_barrier(0);
  loadA(1, rA[1]);
  __builtin_amdgcn_sched_barrier(0);
  stageB(1, 1);
  __builtin_amdgcn_sched_barrier(0);
  asm volatile("s_waitcnt vmcnt(6)" ::: "memory");   // slot-0 group landed
  writeA(0, rA[0]);
  asm volatile("s_waitcnt lgkmcnt(0)" ::: "memory");
  __builtin_amdgcn_s_barrier();

  // ---- 16 slots, fully unrolled ----
  #pragma unroll
  for (int s = 0; s < 16; ++s) {
    const int bufR = s % 3;
    const char* aB = smem + bufR * 8192;
    const char* bB = smem + 24576 + bufR * 16384;

    // frag reads (slot s)
    f16x8 af[2][2], bf[2][4];
    #pragma unroll
    for (int kk = 0; kk < 2; ++kk) {
      #pragma unroll
      for (int m = 0; m < 2; ++m) {
        int row = wm * 32 + m * 16 + lr;
        int cp  = (kk * 4 + hi) ^ (row & 7);
        af[kk][m] = *(const f16x8*)(aB + row * 128 + cp * 16);
      }
      #pragma unroll
      for (int n = 0; n < 4; ++n) {
        int row = wn * 64 + n * 16 + lr;
        int cp  = (kk * 4 + hi) ^ (row & 7);
        bf[kk][n] = *(const f16x8*)(bB + row * 128 + cp * 16);
      }
    }

    if (s + 2 < 16) {                      // issue slot s+2 (6 VM ops)
      loadA(s + 2, rA[s & 1]);             // (s+2)&1 == s&1
      __builtin_amdgcn_sched_barrier(0);
      stageB(s + 2, (s + 2) % 3);
      __builtin_amdgcn_sched_barrier(0);
    }

    __builtin_amdgcn_s_setprio(1);
    #pragma unroll
    for (int kk = 0; kk < 2; ++kk)
      #pragma unroll
      for (int m = 0; m < 2; ++m)
        #pragma unroll
        for (int n = 0; n < 4; ++n)
          acc[m][n] = __builtin_amdgcn_mfma_f32_16x16x32_f16(
              af[kk][m], bf[kk][n], acc[m][n], 0, 0, 0);
    __builtin_amdgcn_s_setprio(0);

    if (s < 15) {
      if (s <= 13) asm volatile("s_waitcnt vmcnt(6)" ::: "memory");
      else         asm volatile("s_waitcnt vmcnt(0)" ::: "memory");
      writeA((s + 1) % 3, rA[(s + 1) & 1]);
      asm volatile("s_waitcnt lgkmcnt(0)" ::: "memory");
      __builtin_amdgcn_s_barrier();
    }
  }

  // ---- epilogue: f32 + bias. C/D: col = lane&15, row = (lane>>4)*4+reg ----
  float bv[4];
  #pragma unroll
  for (int n = 0; n < 4; ++n) bv[n] = bias[J0 + wn * 64 + n * 16 + lr];
  #pragma unroll
  for (int m = 0; m < 2; ++m) {
    #pragma unroll
    for (int i = 0; i < 4; ++i) {
      int r = q0 + wm * 32 + m * 16 + (hi << 2) + i;
      #pragma unroll
      for (int n = 0; n < 4; ++n)
        ob[(size_t)r * P_ + J0 + wn * 64 + n * 16 + lr] = acc[m][n][i] + bv[n];
    }
  }
}

// ---------------------------------------------------------------------------
// VW GEMM (frozen — identical to rounds 7-9): C[MxN] = A[MxK]*B[NxK]^T, f16.
// ---------------------------------------------------------------------------
template<int KK, int BM, int BN, int NW, int WNS>
__global__ __launch_bounds__(NW * 64, 2) void gemm_nt_small(
    const u16* __restrict__ A, const u16* __restrict__ Bm,
    u16* __restrict__ C, long sAb, long sBb, long sCb, int LDC) {
  constexpr int T   = NW * 64;
  constexpr int WMS = NW / WNS;
  constexpr int MF  = BM / (WMS * 16);
  constexpr int NF  = BN / (WNS * 16);
  constexpr int LA  = BM * 8 / T;
  constexpr int LB  = BN * 8 / T;
  constexpr int SZ  = (BM + BN) * 128;
  constexpr int NT  = KK / 64;

  extern __shared__ __align__(16) char smem[];
  const int tid  = threadIdx.x;
  const int lane = tid & 63;
  const int w    = tid >> 6;
  const int wm   = w / WNS;
  const int wn   = w % WNS;
  const int lr   = lane & 15;
  const int hi   = lane >> 4;

  const int bz = blockIdx.z;
  const int I0 = blockIdx.y * BM;
  const int J0 = blockIdx.x * BN;
  const u16* Ab = A  + (long)bz * sAb;
  const u16* Bb = Bm + (long)bz * sBb;

  auto stage = [&](int buf, int k0) {
    char* sA = smem + buf * SZ;
    char* sB = sA + BM * 128;
    #pragma unroll
    for (int i = 0; i < LA; ++i) {
      int cid = i * T + tid;
      int row = cid >> 3;
      int c   = (cid & 7) ^ (row & 7);
      gld_lds16(Ab + (size_t)(I0 + row) * KK + k0 + c * 8, sA + cid * 16);
    }
    #pragma unroll
    for (int i = 0; i < LB; ++i) {
      int cid = i * T + tid;
      int row = cid >> 3;
      int c   = (cid & 7) ^ (row & 7);
      gld_lds16(Bb + (size_t)(J0 + row) * KK + k0 + c * 8, sB + cid * 16);
    }
  };

  f32x4 acc[MF][NF] = {};
  stage(0, 0);
  for (int t = 0; t < NT; ++t) {
    const char* lA = smem + (t & 1) * SZ;
    const char* lB = lA + BM * 128;
    if (t + 1 < NT) {
      stage((t + 1) & 1, (t + 1) * 64);
      asm volatile("s_waitcnt vmcnt(%0)" :: "i"(LA + LB) : "memory");
    } else {
      asm volatile("s_waitcnt vmcnt(0)" ::: "memory");
    }
    __builtin_amdgcn_s_barrier();
    __builtin_amdgcn_sched_barrier(0);
    #pragma unroll
    for (int kk = 0; kk < 2; ++kk) {
      f16x8 af[MF], bfv[NF];
      #pragma unroll
      for (int m = 0; m < MF; ++m) {
        int row = wm * (MF * 16) + m * 16 + lr;
        int cp  = (kk * 4 + hi) ^ (row & 7);
        af[m] = *(const f16x8*)(lA + ((row * 8 + cp) << 4));
      }
      #pragma unroll
      for (int n = 0; n < NF; ++n) {
        int row = wn * (NF * 16) + n * 16 + lr;
        int cp  = (kk * 4 + hi) ^ (row & 7);
        bfv[n] = *(const f16x8*)(lB + ((row * 8 + cp) << 4));
      }
      __builtin_amdgcn_s_setprio(1);
      #pragma unroll
      for (int m = 0; m < MF; ++m)
        #pragma unroll
        for (int n = 0; n < NF; ++n)
          acc[m][n] = __builtin_amdgcn_mfma_f32_16x16x32_f16(af[m], bfv[n], acc[m][n], 0, 0, 0);
      __builtin_amdgcn_s_setprio(0);
    }
    __builtin_amdgcn_sched_barrier(0);
    __builtin_amdgcn_s_barrier();
  }

  const int row0 = I0 + wm * (MF * 16);
  const int col0 = J0 + wn * (NF * 16);
  #pragma unroll
  for (int m = 0; m < MF; ++m)
    #pragma unroll
    for (int i = 0; i < 4; ++i) {
      int r = row0 + m * 16 + (hi << 2) + i;
      #pragma unroll
      for (int n = 0; n < NF; ++n)
        C[(long)bz * sCb + (size_t)r * LDC + col0 + n * 16 + lr] = f2h(acc[m][n][i]);
    }
}

// ---------------------------------------------------------------------------
extern "C" void kernel_launch(void* const* d_in, const int* in_sizes, int n_in,
                              void* d_out, int out_size, void* d_ws, size_t ws_size,
                              hipStream_t stream) {
  const float* data = (const float*)d_in[0];   // [16][1024][512]
  const float* W    = (const float*)d_in[1];   // [256][512]
  const float* bias = (const float*)d_in[2];   // [256]
  float* out = (float*)d_out;                  // [16][2048][256]
  char*  ws  = (char*)d_ws;

  const size_t MB = 1024 * 1024;
  u16*    dataH   = (u16*)(ws);                // 16 MB  [B][S][D] f16
  u16*    Wh      = (u16*)(ws + 16 * MB);      // 256 KB [P][D] f16
  u16*    scoresH = (u16*)(ws + 17 * MB);      // 32 MB  [B][S][S] f16
  u16*    VWT     = (u16*)(ws + 49 * MB);      // 8 MB   [B][P][S] f16
  float2* rowstat = (float2*)(ws + 57 * MB);   // 128 KB [B][S] (m, 1/l)

  const float scale = 0.04419417382415922f;    // 1/sqrt(512)

  constexpr int SMEM_QK = 4 * 32768;             // 128 KB
  constexpr int SMEM_PV = 3 * 8192 + 3 * 16384;  // 72 KB
  constexpr int SMEM_VW = 2 * (64 + 128) * 128;  // 48 KB

  (void)hipFuncSetAttribute((const void*)&qk_pipe,
                      hipFuncAttributeMaxDynamicSharedMemorySize, SMEM_QK);
  (void)hipFuncSetAttribute((const void*)&pv_slot,
                      hipFuncAttributeMaxDynamicSharedMemorySize, SMEM_PV);
  (void)hipFuncSetAttribute((const void*)&gemm_nt_small<512, 64, 128, 4, 2>,
                      hipFuncAttributeMaxDynamicSharedMemorySize, SMEM_VW);

  convert_f16_kernel<<<2048, 256, 0, stream>>>(data, dataH, (long)B_ * S_ * D_ / 4);
  convert_f16_kernel<<<64, 256, 0, stream>>>(W, Wh, (long)P_ * D_ / 4);

  // VWT[b] = Wh (256x512) @ dataH[b]^T -> [256][1024] f16
  gemm_nt_small<512, 64, 128, 4, 2><<<dim3(8, 4, 16), 256, SMEM_VW, stream>>>(
      Wh, dataH, VWT, 0L, (long)S_ * D_, (long)P_ * S_, S_);

  // scoresH[b] = scale * dataH[b] @ dataH[b]^T -> [1024][1024] f16
  qk_pipe<<<dim3(4, 4, 16), 512, SMEM_QK, stream>>>(dataH, scoresH, scale);

  // rowstat = per-row (max, 1/sumexp)
  stats_kernel<<<4096, 256, 0, stream>>>(scoresH, rowstat);

  // out[b][:S] = softmax(scoresH[b]) @ VWT[b]^T + bias; tail rows zeroed
  pv_slot<<<dim3(2, 32, 16), 256, SMEM_PV, stream>>>(
      scoresH, VWT, rowstat, out, bias);
}

// Round 11
// 78.411 us; speedup vs baseline: 1.8559x; 1.0640x over previous
//
#include <hip/hip_runtime.h>
#include <cstdint>
#include <cstddef>

// Problem constants
#define B_    16
#define S_    1024
#define D_    512
#define P_    256
#define MAXS_ 2048

typedef unsigned short u16;
typedef unsigned int   u32;
typedef _Float16 f16;
typedef _Float16 f16x8 __attribute__((ext_vector_type(8)));
typedef float  f32x4  __attribute__((ext_vector_type(4)));
typedef unsigned short u16x4 __attribute__((ext_vector_type(4)));
typedef unsigned short u16x8 __attribute__((ext_vector_type(8)));

__device__ __forceinline__ void gld_lds16(const void* g, void* l) {
  __builtin_amdgcn_global_load_lds(
      (const __attribute__((address_space(1))) u32*)g,
      (__attribute__((address_space(3))) u32*)l, 16, 0, 0);
}

__device__ __forceinline__ u16 f2h(float f) {
  return __builtin_bit_cast(u16, (f16)f);
}
__device__ __forceinline__ float h2f(u16 h) {
  return (float)__builtin_bit_cast(f16, h);
}

// Batch-affinity XCD swizzle: hardware XCD = linear_block_id % 8 (round-robin
// model, T1). Map so XCD t owns ALL blocks of batches 2t and 2t+1 -> per-XCD
// L2 working set = 2 batches' panels. Bijective since nwg % 8 == 0 and
// nwg == 32 * BPB (16 batches x BPB blocks each).
template<int BPB>
__device__ __forceinline__ void xcd_map(int L, int& bz, int& r) {
  const int t = L & 7;
  const int j = L >> 3;            // 0 .. 2*BPB-1 within this XCD
  bz = (t << 1) | (j / BPB);
  r  = j % BPB;
}

// ---------------------------------------------------------------------------
// f32 -> f16 convert (data, W)  [frozen]
// ---------------------------------------------------------------------------
__global__ void convert_f16_kernel(const float* __restrict__ src, u16* __restrict__ dst, long n4) {
  long stride = (long)gridDim.x * blockDim.x;
  for (long i = (long)blockIdx.x * blockDim.x + threadIdx.x; i < n4; i += stride) {
    float4 v = ((const float4*)src)[i];
    u16x4 o;
    o[0] = f2h(v.x); o[1] = f2h(v.y); o[2] = f2h(v.z); o[3] = f2h(v.w);
    ((u16x4*)dst)[i] = o;
  }
}

// ---------------------------------------------------------------------------
// QK^T, slot-pipelined. Body frozen (rounds 5-10); ONLY the block->work
// decode changed: batch-affinity XCD swizzle (grid (4,4,16), BPB=16).
// ---------------------------------------------------------------------------
__global__ __launch_bounds__(512, 2) void qk_pipe(
    const u16* __restrict__ A, u16* __restrict__ Cout, float scale) {
  extern __shared__ __align__(16) char smem[];   // 4 * 32768
  const int tid  = threadIdx.x;
  const int lane = tid & 63;
  const int w    = tid >> 6;
  const int wm   = w >> 2;        // 0..1
  const int wn   = w & 3;         // 0..3
  const int lr   = lane & 15;
  const int hi   = lane >> 4;

  const int L = blockIdx.x + (blockIdx.y << 2) + (blockIdx.z << 4);
  int bz, r;
  xcd_map<16>(L, bz, r);
  const int I0 = (r >> 2) * 256;
  const int J0 = (r & 3) * 256;
  const u16* Ab = A + (long)bz * (S_ * D_);

  auto stageP = [&](int s, int part) {
    if (s >= 16) return;
    char* dst = smem + (s & 3) * 32768 + part * 16384;
    const int base = part ? J0 : I0;
    const int k0 = s * 32;
    #pragma unroll
    for (int i = 0; i < 2; ++i) {
      int cid   = i * 512 + tid;
      int inner = cid >> 2;
      int c     = (cid & 3) ^ ((inner >> 1) & 3);
      gld_lds16(Ab + (size_t)(base + inner) * D_ + k0 + c * 8, dst + cid * 16);
    }
  };

  f32x4 acc[8][4] = {};

  stageP(0, 0); stageP(0, 1);
  stageP(1, 0); stageP(1, 1);
  stageP(2, 0); stageP(2, 1);
  asm volatile("s_waitcnt vmcnt(8)" ::: "memory");
  __builtin_amdgcn_s_barrier();

  for (int s = 0; s < 16; ++s) {
    const char* sl = smem + (s & 3) * 32768;
    f16x8 bf[4];
    // ---- phase 0 ----
    {
      f16x8 af[4];
      #pragma unroll
      for (int mq = 0; mq < 4; ++mq) {
        int row = wm * 128 + mq * 16 + lr;
        int cp  = hi ^ ((row >> 1) & 3);
        af[mq] = *(const f16x8*)(sl + row * 64 + cp * 16);
      }
      #pragma unroll
      for (int n = 0; n < 4; ++n) {
        int row = wn * 64 + n * 16 + lr;
        int cp  = hi ^ ((row >> 1) & 3);
        bf[n] = *(const f16x8*)(sl + 16384 + row * 64 + cp * 16);
      }
      stageP(s + 3, 0);
      __builtin_amdgcn_s_barrier();
      asm volatile("s_waitcnt lgkmcnt(0)" ::: "memory");
      __builtin_amdgcn_sched_barrier(0);
      __builtin_amdgcn_s_setprio(1);
      #pragma unroll
      for (int mq = 0; mq < 4; ++mq)
        #pragma unroll
        for (int n = 0; n < 4; ++n)
          acc[mq][n] = __builtin_amdgcn_mfma_f32_16x16x32_f16(af[mq], bf[n], acc[mq][n], 0, 0, 0);
      __builtin_amdgcn_s_setprio(0);
      __builtin_amdgcn_s_barrier();
    }
    // ---- phase 1 ----
    {
      f16x8 af[4];
      #pragma unroll
      for (int mq = 0; mq < 4; ++mq) {
        int row = wm * 128 + 64 + mq * 16 + lr;
        int cp  = hi ^ ((row >> 1) & 3);
        af[mq] = *(const f16x8*)(sl + row * 64 + cp * 16);
      }
      stageP(s + 3, 1);
      __builtin_amdgcn_s_barrier();
      asm volatile("s_waitcnt lgkmcnt(0)" ::: "memory");
      __builtin_amdgcn_sched_barrier(0);
      __builtin_amdgcn_s_setprio(1);
      #pragma unroll
      for (int mq = 0; mq < 4; ++mq)
        #pragma unroll
        for (int n = 0; n < 4; ++n)
          acc[4 + mq][n] = __builtin_amdgcn_mfma_f32_16x16x32_f16(af[mq], bf[n], acc[4 + mq][n], 0, 0, 0);
      __builtin_amdgcn_s_setprio(0);
      if (s <= 12)      asm volatile("s_waitcnt vmcnt(8)" ::: "memory");
      else if (s == 13) asm volatile("s_waitcnt vmcnt(4)" ::: "memory");
      else if (s == 14) asm volatile("s_waitcnt vmcnt(0)" ::: "memory");
      __builtin_amdgcn_s_barrier();
    }
  }

  u16* Cb = Cout + (long)bz * S_ * S_;
  const int row0 = I0 + wm * 128;
  const int col0 = J0 + wn * 64;
  #pragma unroll
  for (int m = 0; m < 8; ++m) {
    #pragma unroll
    for (int i = 0; i < 4; ++i) {
      int rr = row0 + m * 16 + (hi << 2) + i;
      #pragma unroll
      for (int n = 0; n < 4; ++n) {
        int c = col0 + n * 16 + lr;
        Cb[(size_t)rr * S_ + c] = f2h(acc[m][n][i] * scale);
      }
    }
  }
}

// ---------------------------------------------------------------------------
// Row stats. Body frozen; decode swizzled (grid 4096, BPB=256 blocks/batch).
// Reads scores[b] on the XCD that wrote them (possible L2 carry-over).
// ---------------------------------------------------------------------------
__global__ __launch_bounds__(256) void stats_kernel(
    const u16* __restrict__ scores, float2* __restrict__ rowstat) {
  const int lane = threadIdx.x & 63;
  const int wv   = threadIdx.x >> 6;
  int bz, r;
  xcd_map<256>(blockIdx.x, bz, r);
  const long row = ((long)bz * 256 + r) * 4 + wv;
  const u16* src = scores + row * S_;

  u16x8 a0 = *(const u16x8*)&src[lane * 16];
  u16x8 a1 = *(const u16x8*)&src[lane * 16 + 8];
  float v[16];
  #pragma unroll
  for (int j = 0; j < 8; ++j) { v[j] = h2f(a0[j]); v[8 + j] = h2f(a1[j]); }

  float mx = v[0];
  #pragma unroll
  for (int j = 1; j < 16; ++j) mx = fmaxf(mx, v[j]);
  #pragma unroll
  for (int off = 32; off > 0; off >>= 1)
    mx = fmaxf(mx, __shfl_xor(mx, off));

  const float l2e = 1.4426950408889634f;
  float sum = 0.f;
  #pragma unroll
  for (int j = 0; j < 16; ++j) sum += exp2f((v[j] - mx) * l2e);
  #pragma unroll
  for (int off = 32; off > 0; off >>= 1)
    sum += __shfl_xor(sum, off);

  if (lane == 0) rowstat[row] = make_float2(mx, 1.f / sum);
}

// ---------------------------------------------------------------------------
// pv_slot. Body frozen (round 10); decode swizzled (grid (2,32,16), BPB=64).
// VWT[b] (512 KB) now L2-resident per XCD instead of refetched 8x.
// ---------------------------------------------------------------------------
__global__ __launch_bounds__(256, 2) void pv_slot(
    const u16* __restrict__ scores, const u16* __restrict__ VWT,
    const float2* __restrict__ rowstat,
    float* __restrict__ out, const float* __restrict__ bias) {
  extern __shared__ __align__(16) char smem[];   // A 3*8K @0, B 3*16K @24K
  const int tid  = threadIdx.x;
  const int lane = tid & 63;
  const int w    = tid >> 6;
  const int wm   = w >> 1;        // 0..1
  const int wn   = w & 1;         // 0..1
  const int lr   = lane & 15;
  const int hi   = lane >> 4;

  const int L = blockIdx.x + (blockIdx.y << 1) + (blockIdx.z << 6);
  int bz, rblk;
  xcd_map<64>(L, bz, rblk);
  const int yt = rblk >> 1;
  const int J0 = (rblk & 1) * 128;

  float* ob = out + (long)bz * MAXS_ * P_;
  if (yt >= 16) {                  // zero rows [yt*64,+64) x cols [J0,+128)
    #pragma unroll 2
    for (int i = tid; i < 64 * 32; i += 256) {
      int rr = i >> 5;
      int c4 = i & 31;
      *((float4*)(ob + (size_t)(yt * 64 + rr) * P_ + J0) + c4) =
          make_float4(0.f, 0.f, 0.f, 0.f);
    }
    return;
  }

  const int q0 = yt * 64;
  const u16* sA = scores + ((long)bz * S_ + q0) * S_;
  const u16* Vb = VWT + (long)bz * P_ * S_ + (size_t)J0 * S_;
  const float l2e = 1.4426950408889634f;

  const int ar0 = tid >> 3;
  const int ar1 = 32 + (tid >> 3);
  const int ac  = tid & 7;
  const int c0  = ac ^ (ar0 & 7);
  const int c1  = ac ^ (ar1 & 7);
  const float2 st0 = rowstat[(long)bz * S_ + q0 + ar0];
  const float2 st1 = rowstat[(long)bz * S_ + q0 + ar1];
  const float nml0 = -st0.x * l2e, il0 = st0.y;
  const float nml1 = -st1.x * l2e, il1 = st1.y;

  auto loadA = [&](int s, u16x8 (&r)[2]) {
    r[0] = *(const u16x8*)(sA + (size_t)ar0 * S_ + s * 64 + c0 * 8);
    r[1] = *(const u16x8*)(sA + (size_t)ar1 * S_ + s * 64 + c1 * 8);
  };
  auto writeA = [&](int buf, u16x8 (&r)[2]) {
    char* dA = smem + buf * 8192;
    u16x8 p0, p1;
    #pragma unroll
    for (int j = 0; j < 8; ++j) {
      p0[j] = f2h(exp2f(fmaf(h2f(r[0][j]), l2e, nml0)) * il0);
      p1[j] = f2h(exp2f(fmaf(h2f(r[1][j]), l2e, nml1)) * il1);
    }
    *(u16x8*)(dA + (size_t)tid * 16)         = p0;
    *(u16x8*)(dA + (size_t)(256 + tid) * 16) = p1;
  };
  auto stageB = [&](int s, int buf) {
    char* dB = smem + 24576 + buf * 16384;
    #pragma unroll
    for (int i = 0; i < 4; ++i) {
      int cid = i * 256 + tid;
      int row = cid >> 3;
      int c   = (cid & 7) ^ (row & 7);
      gld_lds16(Vb + (size_t)row * S_ + s * 64 + c * 8, dB + cid * 16);
    }
  };

  f32x4 acc[2][4] = {};
  u16x8 rA[2][2];

  loadA(0, rA[0]);
  __builtin_amdgcn_sched_barrier(0);
  stageB(0, 0);
  __builtin_amdgcn_sched_barrier(0);
  loadA(1, rA[1]);
  __builtin_amdgcn_sched_barrier(0);
  stageB(1, 1);
  __builtin_amdgcn_sched_barrier(0);
  asm volatile("s_waitcnt vmcnt(6)" ::: "memory");
  writeA(0, rA[0]);
  asm volatile("s_waitcnt lgkmcnt(0)" ::: "memory");
  __builtin_amdgcn_s_barrier();

  #pragma unroll
  for (int s = 0; s < 16; ++s) {
    const int bufR = s % 3;
    const char* aB = smem + bufR * 8192;
    const char* bB = smem + 24576 + bufR * 16384;

    f16x8 af[2][2], bf[2][4];
    #pragma unroll
    for (int kk = 0; kk < 2; ++kk) {
      #pragma unroll
      for (int m = 0; m < 2; ++m) {
        int row = wm * 32 + m * 16 + lr;
        int cp  = (kk * 4 + hi) ^ (row & 7);
        af[kk][m] = *(const f16x8*)(aB + row * 128 + cp * 16);
      }
      #pragma unroll
      for (int n = 0; n < 4; ++n) {
        int row = wn * 64 + n * 16 + lr;
        int cp  = (kk * 4 + hi) ^ (row & 7);
        bf[kk][n] = *(const f16x8*)(bB + row * 128 + cp * 16);
      }
    }

    if (s + 2 < 16) {
      loadA(s + 2, rA[s & 1]);
      __builtin_amdgcn_sched_barrier(0);
      stageB(s + 2, (s + 2) % 3);
      __builtin_amdgcn_sched_barrier(0);
    }

    __builtin_amdgcn_s_setprio(1);
    #pragma unroll
    for (int kk = 0; kk < 2; ++kk)
      #pragma unroll
      for (int m = 0; m < 2; ++m)
        #pragma unroll
        for (int n = 0; n < 4; ++n)
          acc[m][n] = __builtin_amdgcn_mfma_f32_16x16x32_f16(
              af[kk][m], bf[kk][n], acc[m][n], 0, 0, 0);
    __builtin_amdgcn_s_setprio(0);

    if (s < 15) {
      if (s <= 13) asm volatile("s_waitcnt vmcnt(6)" ::: "memory");
      else         asm volatile("s_waitcnt vmcnt(0)" ::: "memory");
      writeA((s + 1) % 3, rA[(s + 1) & 1]);
      asm volatile("s_waitcnt lgkmcnt(0)" ::: "memory");
      __builtin_amdgcn_s_barrier();
    }
  }

  float bv[4];
  #pragma unroll
  for (int n = 0; n < 4; ++n) bv[n] = bias[J0 + wn * 64 + n * 16 + lr];
  #pragma unroll
  for (int m = 0; m < 2; ++m) {
    #pragma unroll
    for (int i = 0; i < 4; ++i) {
      int rr = q0 + wm * 32 + m * 16 + (hi << 2) + i;
      #pragma unroll
      for (int n = 0; n < 4; ++n)
        ob[(size_t)rr * P_ + J0 + wn * 64 + n * 16 + lr] = acc[m][n][i] + bv[n];
    }
  }
}

// ---------------------------------------------------------------------------
// VW GEMM. Body frozen; decode swizzled (grid (8,4,16), BPB=32).
// ---------------------------------------------------------------------------
template<int KK, int BM, int BN, int NW, int WNS, int BPB>
__global__ __launch_bounds__(NW * 64, 2) void gemm_nt_small(
    const u16* __restrict__ A, const u16* __restrict__ Bm,
    u16* __restrict__ C, long sAb, long sBb, long sCb, int LDC) {
  constexpr int T   = NW * 64;
  constexpr int WMS = NW / WNS;
  constexpr int MF  = BM / (WMS * 16);
  constexpr int NF  = BN / (WNS * 16);
  constexpr int LA  = BM * 8 / T;
  constexpr int LB  = BN * 8 / T;
  constexpr int SZ  = (BM + BN) * 128;
  constexpr int NT  = KK / 64;

  extern __shared__ __align__(16) char smem[];
  const int tid  = threadIdx.x;
  const int lane = tid & 63;
  const int w    = tid >> 6;
  const int wm   = w / WNS;
  const int wn   = w % WNS;
  const int lr   = lane & 15;
  const int hi   = lane >> 4;

  const int L = blockIdx.x + gridDim.x * (blockIdx.y + gridDim.y * blockIdx.z);
  int bz, r;
  xcd_map<BPB>(L, bz, r);
  const int I0 = (r / gridDim.x) * BM;
  const int J0 = (r % gridDim.x) * BN;
  const u16* Ab = A  + (long)bz * sAb;
  const u16* Bb = Bm + (long)bz * sBb;

  auto stage = [&](int buf, int k0) {
    char* sA = smem + buf * SZ;
    char* sB = sA + BM * 128;
    #pragma unroll
    for (int i = 0; i < LA; ++i) {
      int cid = i * T + tid;
      int row = cid >> 3;
      int c   = (cid & 7) ^ (row & 7);
      gld_lds16(Ab + (size_t)(I0 + row) * KK + k0 + c * 8, sA + cid * 16);
    }
    #pragma unroll
    for (int i = 0; i < LB; ++i) {
      int cid = i * T + tid;
      int row = cid >> 3;
      int c   = (cid & 7) ^ (row & 7);
      gld_lds16(Bb + (size_t)(J0 + row) * KK + k0 + c * 8, sB + cid * 16);
    }
  };

  f32x4 acc[MF][NF] = {};
  stage(0, 0);
  for (int t = 0; t < NT; ++t) {
    const char* lA = smem + (t & 1) * SZ;
    const char* lB = lA + BM * 128;
    if (t + 1 < NT) {
      stage((t + 1) & 1, (t + 1) * 64);
      asm volatile("s_waitcnt vmcnt(%0)" :: "i"(LA + LB) : "memory");
    } else {
      asm volatile("s_waitcnt vmcnt(0)" ::: "memory");
    }
    __builtin_amdgcn_s_barrier();
    __builtin_amdgcn_sched_barrier(0);
    #pragma unroll
    for (int kk = 0; kk < 2; ++kk) {
      f16x8 af[MF], bfv[NF];
      #pragma unroll
      for (int m = 0; m < MF; ++m) {
        int row = wm * (MF * 16) + m * 16 + lr;
        int cp  = (kk * 4 + hi) ^ (row & 7);
        af[m] = *(const f16x8*)(lA + ((row * 8 + cp) << 4));
      }
      #pragma unroll
      for (int n = 0; n < NF; ++n) {
        int row = wn * (NF * 16) + n * 16 + lr;
        int cp  = (kk * 4 + hi) ^ (row & 7);
        bfv[n] = *(const f16x8*)(lB + ((row * 8 + cp) << 4));
      }
      __builtin_amdgcn_s_setprio(1);
      #pragma unroll
      for (int m = 0; m < MF; ++m)
        #pragma unroll
        for (int n = 0; n < NF; ++n)
          acc[m][n] = __builtin_amdgcn_mfma_f32_16x16x32_f16(af[m], bfv[n], acc[m][n], 0, 0, 0);
      __builtin_amdgcn_s_setprio(0);
    }
    __builtin_amdgcn_sched_barrier(0);
    __builtin_amdgcn_s_barrier();
  }

  const int row0 = I0 + wm * (MF * 16);
  const int col0 = J0 + wn * (NF * 16);
  #pragma unroll
  for (int m = 0; m < MF; ++m)
    #pragma unroll
    for (int i = 0; i < 4; ++i) {
      int rr = row0 + m * 16 + (hi << 2) + i;
      #pragma unroll
      for (int n = 0; n < NF; ++n)
        C[(long)bz * sCb + (size_t)rr * LDC + col0 + n * 16 + lr] = f2h(acc[m][n][i]);
    }
}

// ---------------------------------------------------------------------------
extern "C" void kernel_launch(void* const* d_in, const int* in_sizes, int n_in,
                              void* d_out, int out_size, void* d_ws, size_t ws_size,
                              hipStream_t stream) {
  const float* data = (const float*)d_in[0];   // [16][1024][512]
  const float* W    = (const float*)d_in[1];   // [256][512]
  const float* bias = (const float*)d_in[2];   // [256]
  float* out = (float*)d_out;                  // [16][2048][256]
  char*  ws  = (char*)d_ws;

  const size_t MB = 1024 * 1024;
  u16*    dataH   = (u16*)(ws);                // 16 MB  [B][S][D] f16
  u16*    Wh      = (u16*)(ws + 16 * MB);      // 256 KB [P][D] f16
  u16*    scoresH = (u16*)(ws + 17 * MB);      // 32 MB  [B][S][S] f16
  u16*    VWT     = (u16*)(ws + 49 * MB);      // 8 MB   [B][P][S] f16
  float2* rowstat = (float2*)(ws + 57 * MB);   // 128 KB [B][S] (m, 1/l)

  const float scale = 0.04419417382415922f;    // 1/sqrt(512)

  constexpr int SMEM_QK = 4 * 32768;             // 128 KB
  constexpr int SMEM_PV = 3 * 8192 + 3 * 16384;  // 72 KB
  constexpr int SMEM_VW = 2 * (64 + 128) * 128;  // 48 KB

  (void)hipFuncSetAttribute((const void*)&qk_pipe,
                      hipFuncAttributeMaxDynamicSharedMemorySize, SMEM_QK);
  (void)hipFuncSetAttribute((const void*)&pv_slot,
                      hipFuncAttributeMaxDynamicSharedMemorySize, SMEM_PV);
  (void)hipFuncSetAttribute((const void*)&gemm_nt_small<512, 64, 128, 4, 2, 32>,
                      hipFuncAttributeMaxDynamicSharedMemorySize, SMEM_VW);

  convert_f16_kernel<<<2048, 256, 0, stream>>>(data, dataH, (long)B_ * S_ * D_ / 4);
  convert_f16_kernel<<<64, 256, 0, stream>>>(W, Wh, (long)P_ * D_ / 4);

  // VWT[b] = Wh (256x512) @ dataH[b]^T -> [256][1024] f16
  gemm_nt_small<512, 64, 128, 4, 2, 32><<<dim3(8, 4, 16), 256, SMEM_VW, stream>>>(
      Wh, dataH, VWT, 0L, (long)S_ * D_, (long)P_ * S_, S_);

  // scoresH[b] = scale * dataH[b] @ dataH[b]^T -> [1024][1024] f16
  qk_pipe<<<dim3(4, 4, 16), 512, SMEM_QK, stream>>>(dataH, scoresH, scale);

  // rowstat = per-row (max, 1/sumexp)
  stats_kernel<<<4096, 256, 0, stream>>>(scoresH, rowstat);

  // out[b][:S] = softmax(scoresH[b]) @ VWT[b]^T + bias; tail rows zeroed
  pv_slot<<<dim3(2, 32, 16), 256, SMEM_PV, stream>>>(
      scoresH, VWT, rowstat, out, bias);
}